// Round 11
// baseline (245.491 us; speedup 1.0000x reference)
//
#include <hip/hip_runtime.h>
#include <hip/hip_fp16.h>

#define NN 100000
#define NE 1600000
#define FI 32
#define FH 30
#define PAD 32       // row stride (halfs) for all fp16 feature arrays
#define NG 512
#define NBK 782      // ceil(NN/128) buckets of 128 consecutive dst nodes
#define BNODES 128
#define SCB 2048     // blocks for hist/scatter grid-stride
#define CBLK 32      // blocks per prefix chunk
#define NCHUNK (SCB / CBLK)   // 64
#define CAP 4096     // per-bucket LDS staging capacity (mean 2046)
#define AB 25000     // NN/4 blocks for fused layer kernels (one wave per node)

// ---------- per-block bucket histogram: partial[blk][bucket], no init required ----------
__global__ __launch_bounds__(256) void k_phist(const int* __restrict__ dst, int* __restrict__ partial)
{
    __shared__ int cnt[NBK];
    for (int i = threadIdx.x; i < NBK; i += 256) cnt[i] = 0;
    __syncthreads();
    for (int e = blockIdx.x * 256 + threadIdx.x; e < NE; e += SCB * 256)
        atomicAdd(&cnt[dst[e] >> 7], 1);
    __syncthreads();
    for (int i = threadIdx.x; i < NBK; i += 256)
        partial[(size_t)blockIdx.x * NBK + i] = cnt[i];
}

// ---------- chunk sums: chunksum[c][b] = sum of partial over CBLK blocks ----------
__global__ __launch_bounds__(256) void k_csum(const int* __restrict__ partial, int* __restrict__ chunksum)
{
    int t = blockIdx.x * 256 + threadIdx.x;
    if (t >= NCHUNK * NBK) return;
    int c = t / NBK, b = t - c * NBK;
    int s = 0;
    #pragma unroll 8
    for (int k = 0; k < CBLK; ++k)
        s += partial[(size_t)(c * CBLK + k) * NBK + b];
    chunksum[c * NBK + b] = s;
}

// ---------- bucket scan: bktOff (exclusive over buckets) + per-chunk bases ----------
__global__ __launch_bounds__(1024) void k_cscan(const int* __restrict__ chunksum,
                                                int* __restrict__ chunkbase, int* __restrict__ bktOff)
{
    __shared__ int tmp[1024];
    int tid = threadIdx.x;
    int total = 0;
    if (tid < NBK) {
        for (int c = 0; c < NCHUNK; ++c) total += chunksum[c * NBK + tid];
    }
    tmp[tid] = (tid < NBK) ? total : 0;
    __syncthreads();
    for (int off = 1; off < 1024; off <<= 1) {
        int t = (tid >= off) ? tmp[tid - off] : 0;
        __syncthreads();
        tmp[tid] += t;
        __syncthreads();
    }
    if (tid < NBK) {
        int run = tmp[tid] - total;   // exclusive bucket offset
        bktOff[tid] = run;
        for (int c = 0; c < NCHUNK; ++c) {
            chunkbase[c * NBK + tid] = run;
            run += chunksum[c * NBK + tid];
        }
    }
    if (tid == 0) bktOff[NBK] = NE;
}

// ---------- per-block bases: partial[blk][b] <- global write base (in-place prefix) ----------
__global__ __launch_bounds__(256) void k_base(int* __restrict__ partial, const int* __restrict__ chunkbase)
{
    int t = blockIdx.x * 256 + threadIdx.x;
    if (t >= NCHUNK * NBK) return;
    int c = t / NBK, b = t - c * NBK;
    int run = chunkbase[c * NBK + b];
    #pragma unroll 8
    for (int k = 0; k < CBLK; ++k) {
        size_t idx = (size_t)(c * CBLK + k) * NBK + b;
        int v = partial[idx];
        partial[idx] = run;
        run += v;
    }
}

// ---------- single-pass bucketed scatter using precomputed bases ----------
__global__ __launch_bounds__(256) void k_bscat(const int* __restrict__ src, const int* __restrict__ dst,
                                               const int* __restrict__ partial, unsigned* __restrict__ pairs)
{
    __shared__ int sbase[NBK];
    __shared__ int scnt[NBK];
    for (int i = threadIdx.x; i < NBK; i += 256) {
        sbase[i] = partial[(size_t)blockIdx.x * NBK + i];
        scnt[i] = 0;
    }
    __syncthreads();
    for (int e = blockIdx.x * 256 + threadIdx.x; e < NE; e += SCB * 256) {
        int d = dst[e];
        int b = d >> 7;
        int r = atomicAdd(&scnt[b], 1);
        pairs[sbase[b] + r] = ((unsigned)src[e] << 7) | (unsigned)(d & 127);
    }
}

// ---------- per-bucket counting sort -> CSR ----------
__global__ __launch_bounds__(256) void k_csr(
    const int* __restrict__ bktOff, const unsigned* __restrict__ pairs,
    int* __restrict__ rowstart, int* __restrict__ col)
{
    __shared__ unsigned sp[CAP];
    __shared__ int bins[BNODES], binpos[BNODES], stmp[BNODES];
    int tid = threadIdx.x;
    int bkt = blockIdx.x;
    int gbase = bktOff[bkt];
    int cnt = bktOff[bkt + 1] - gbase;
    if (tid < BNODES) bins[tid] = 0;
    __syncthreads();
    bool inl = (cnt <= CAP);
    if (inl) {
        for (int i = tid; i < cnt; i += 256) {
            unsigned u = pairs[gbase + i];
            sp[i] = u;
            atomicAdd(&bins[u & 127], 1);
        }
    } else {
        for (int i = tid; i < cnt; i += 256)
            atomicAdd(&bins[pairs[gbase + i] & 127], 1);
    }
    __syncthreads();
    if (tid < BNODES) stmp[tid] = bins[tid];
    __syncthreads();
    for (int off = 1; off < BNODES; off <<= 1) {
        int t = 0;
        if (tid < BNODES && tid >= off) t = stmp[tid - off];
        __syncthreads();
        if (tid < BNODES) stmp[tid] += t;
        __syncthreads();
    }
    if (tid < BNODES) {
        int ex = stmp[tid] - bins[tid];
        binpos[tid] = ex;
        int n = (bkt << 7) + tid;
        if (n < NN) rowstart[n] = gbase + ex;
        if (bkt == 0 && tid == 0) rowstart[NN] = NE;
    }
    __syncthreads();
    if (inl) {
        for (int i = tid; i < cnt; i += 256) {
            unsigned u = sp[i];
            int p = atomicAdd(&binpos[u & 127], 1);
            col[gbase + p] = (int)(u >> 7);
        }
    } else {
        for (int i = tid; i < cnt; i += 256) {
            unsigned u = pairs[gbase + i];
            int p = atomicAdd(&binpos[u & 127], 1);
            col[gbase + p] = (int)(u >> 7);
        }
    }
}

// ---------- fp32 -> fp16 row convert (x -> xh) ----------
__global__ __launch_bounds__(256) void k_tohalf(const float* __restrict__ in, __half2* __restrict__ outp)
{
    int i = blockIdx.x * 256 + threadIdx.x;   // half2 index
    if (i < NN * (PAD / 2)) {
        float2 f = ((const float2*)in)[i];
        outp[i] = __floats2half2_rn(f.x, f.y);
    }
}

// ---------- fused layer: mean-aggregate (CSR gather) + bn(relu(agg@Wl^T+bl+self@Wr^T)) ----------
// one wave per node; 4 lanes/edge x 16B fp16 loads -> 16 row-gathers in flight.
// After butterfly reduce, agg+self rows staged in LDS; 2 lanes per output feature.
// hin doubles as the self-feature array. Output fp16, zero-padded to PAD.
__global__ __launch_bounds__(256) void k_fused(
    const int* __restrict__ rowstart, const int* __restrict__ col,
    const uint4* __restrict__ hin,          // fp16 rows, 4 uint4 each
    const float* __restrict__ Wl, const float* __restrict__ bl, const float* __restrict__ Wr,
    int K,                                  // input feature count (32 or 30)
    const float* __restrict__ g, const float* __restrict__ b,
    const float* __restrict__ m, const float* __restrict__ v,
    __half2* __restrict__ hout)
{
    __shared__ float sWl[FH * 33], sWr[FH * 33];   // stride 33: bank-conflict-free over j
    __shared__ float sBias[FH], sScale[FH], sShift[FH];
    __shared__ float sAgg[4][32], sSelf[4][32];
    int tid = threadIdx.x;
    for (int i = tid; i < FH * 32; i += 256) {
        int j = i >> 5, k = i & 31;
        sWl[j * 33 + k] = (k < K) ? Wl[j * K + k] : 0.0f;
        sWr[j * 33 + k] = (k < K) ? Wr[j * K + k] : 0.0f;
    }
    if (tid < FH) {
        float sc = g[tid] * rsqrtf(v[tid] + 1e-5f);
        sBias[tid] = bl[tid];
        sScale[tid] = sc;
        sShift[tid] = b[tid] - m[tid] * sc;
    }
    __syncthreads();

    int n = (blockIdx.x * 256 + tid) >> 6;      // NN % 4 == 0 -> always valid
    int w = tid >> 6;
    int lane = tid & 63;
    int q = lane & 3;       // uint4 (8-half) block within the 32-half row
    int grp = lane >> 2;    // edge group 0..15
    int rs = rowstart[n], re = rowstart[n + 1];
    float a0 = 0.0f, a1 = 0.0f, a2 = 0.0f, a3 = 0.0f;
    float a4 = 0.0f, a5 = 0.0f, a6 = 0.0f, a7 = 0.0f;
    for (int e = rs + grp; e < re; e += 16) {
        uint4 u = hin[(size_t)col[e] * 4 + q];
        float2 f0 = __half22float2(*(const __half2*)&u.x);
        float2 f1 = __half22float2(*(const __half2*)&u.y);
        float2 f2 = __half22float2(*(const __half2*)&u.z);
        float2 f3 = __half22float2(*(const __half2*)&u.w);
        a0 += f0.x; a1 += f0.y; a2 += f1.x; a3 += f1.y;
        a4 += f2.x; a5 += f2.y; a6 += f3.x; a7 += f3.y;
    }
    #pragma unroll
    for (int off = 4; off < 64; off <<= 1) {
        a0 += __shfl_xor(a0, off); a1 += __shfl_xor(a1, off);
        a2 += __shfl_xor(a2, off); a3 += __shfl_xor(a3, off);
        a4 += __shfl_xor(a4, off); a5 += __shfl_xor(a5, off);
        a6 += __shfl_xor(a6, off); a7 += __shfl_xor(a7, off);
    }
    if (lane < 4) {
        float inv = (re > rs) ? 1.0f / (float)(re - rs) : 0.0f;
        uint4 su = hin[(size_t)n * 4 + q];
        float2 s0 = __half22float2(*(const __half2*)&su.x);
        float2 s1 = __half22float2(*(const __half2*)&su.y);
        float2 s2 = __half22float2(*(const __half2*)&su.z);
        float2 s3 = __half22float2(*(const __half2*)&su.w);
        int base = q * 8;
        sAgg[w][base + 0] = a0 * inv; sAgg[w][base + 1] = a1 * inv;
        sAgg[w][base + 2] = a2 * inv; sAgg[w][base + 3] = a3 * inv;
        sAgg[w][base + 4] = a4 * inv; sAgg[w][base + 5] = a5 * inv;
        sAgg[w][base + 6] = a6 * inv; sAgg[w][base + 7] = a7 * inv;
        sSelf[w][base + 0] = s0.x; sSelf[w][base + 1] = s0.y;
        sSelf[w][base + 2] = s1.x; sSelf[w][base + 3] = s1.y;
        sSelf[w][base + 4] = s2.x; sSelf[w][base + 5] = s2.y;
        sSelf[w][base + 6] = s3.x; sSelf[w][base + 7] = s3.y;
    }
    __syncthreads();

    // phase 2: output feature j = lane>>1, K split across the lane pair
    int j = lane >> 1;
    int k0 = (lane & 1) * 16;
    float partial = 0.0f;
    if (j < FH) {
        #pragma unroll
        for (int k = k0; k < k0 + 16; ++k)
            partial += sAgg[w][k] * sWl[j * 33 + k] + sSelf[w][k] * sWr[j * 33 + k];
    }
    partial += __shfl_xor(partial, 1);
    float res = 0.0f;
    if (j < FH) {
        float acc = fmaxf(partial + sBias[j], 0.0f);
        res = acc * sScale[j] + sShift[j];
    }
    // pack: lane l<16 writes half2 word l = (feature 2l from lane 4l, feature 2l+1 from lane 4l+2)
    int wsel = (lane & 15) * 4;
    float f0 = __shfl(res, wsel);
    float f1 = __shfl(res, wsel + 2);
    if (lane < 16)
        hout[(size_t)n * 16 + lane] = __floats2half2_rn(f0, f1);   // word 15 = (0,0) pad
}

// ---------- per-graph dual pooling + MLP (fp16 input) ----------
__global__ __launch_bounds__(256) void k_pool(
    const __half* __restrict__ h2, const int* __restrict__ batch,
    const float* __restrict__ W1, const float* __restrict__ bb1,
    const float* __restrict__ W2, const float* __restrict__ bb2,
    float* __restrict__ out)
{
    __shared__ float sS[8][FH], sM[8][FH], sz[2 * FH], st[10];
    int tid = threadIdx.x;
    int gi = blockIdx.x;
    int lo = 0, hi = NN;
    while (lo < hi) { int mid = (lo + hi) >> 1; if (batch[mid] < gi) lo = mid + 1; else hi = mid; }
    int start = lo;
    hi = NN;
    while (lo < hi) { int mid = (lo + hi) >> 1; if (batch[mid] <= gi) lo = mid + 1; else hi = mid; }
    int end = lo;

    int f = tid & 31;
    int ng = tid >> 5;
    float sum = 0.0f, mx = -INFINITY;
    if (f < FH) {
        for (int n = start + ng; n < end; n += 8) {
            float val = __half2float(h2[(size_t)n * PAD + f]);
            sum += val;
            mx = fmaxf(mx, val);
        }
        sS[ng][f] = sum;
        sM[ng][f] = mx;
    }
    __syncthreads();
    if (tid < FH) {
        float s = 0.0f, mm = -INFINITY;
        #pragma unroll
        for (int w = 0; w < 8; ++w) { s += sS[w][tid]; mm = fmaxf(mm, sM[w][tid]); }
        int c = end - start;
        sz[tid]      = (c > 0) ? mm : 0.0f;
        sz[FH + tid] = (c > 0) ? s / (float)c : 0.0f;
    }
    __syncthreads();
    if (tid < 10) {
        float t = bb1[tid];
        for (int k = 0; k < 2 * FH; ++k) t += sz[k] * W1[tid * 2 * FH + k];
        st[tid] = fmaxf(t, 0.0f);
    }
    __syncthreads();
    if (tid == 0) {
        float o = bb2[0];
        for (int j = 0; j < 10; ++j) o += st[j] * W2[j];
        out[gi] = 1.0f / (1.0f + expf(-o));
    }
}

extern "C" void kernel_launch(void* const* d_in, const int* in_sizes, int n_in,
                              void* d_out, int out_size, void* d_ws, size_t ws_size,
                              hipStream_t stream)
{
    const float* x   = (const float*)d_in[0];
    const int*   ei  = (const int*)d_in[1];
    const int*   bat = (const int*)d_in[2];
    const float* Wl1 = (const float*)d_in[3];
    const float* bl1 = (const float*)d_in[4];
    const float* Wr1 = (const float*)d_in[5];
    const float* Wl2 = (const float*)d_in[6];
    const float* bl2 = (const float*)d_in[7];
    const float* Wr2 = (const float*)d_in[8];
    const float* g1  = (const float*)d_in[9];
    const float* b1  = (const float*)d_in[10];
    const float* m1  = (const float*)d_in[11];
    const float* v1  = (const float*)d_in[12];
    const float* g2  = (const float*)d_in[13];
    const float* b2  = (const float*)d_in[14];
    const float* m2  = (const float*)d_in[15];
    const float* v2  = (const float*)d_in[16];
    const float* W1  = (const float*)d_in[17];
    const float* bb1 = (const float*)d_in[18];
    const float* W2  = (const float*)d_in[19];
    const float* bb2 = (const float*)d_in[20];

    const int* src = ei;
    const int* dst = ei + NE;

    // workspace layout (4B words; every region starts at a multiple of 4 words = 16B)
    int* wsi = (int*)d_ws;
    int*      partial   = wsi;                              // SCB*NBK
    int*      chunksum  = partial + (size_t)SCB * NBK;      // NCHUNK*NBK
    int*      chunkbase = chunksum + NCHUNK * NBK;          // NCHUNK*NBK
    int*      bktOff    = chunkbase + NCHUNK * NBK;         // NBK+1 (+pad)
    int*      rowstart  = bktOff + NBK + 2;                 // NN+1 (+pad)
    unsigned* pairs     = (unsigned*)(rowstart + NN + 4);   // NE
    int*      col       = (int*)(pairs + NE);               // NE
    __half2*  xh        = (__half2*)(col + NE);             // NN*16 half2
    __half2*  h1h       = xh + (size_t)NN * (PAD / 2);      // NN*16 half2
    __half2*  h2h       = h1h + (size_t)NN * (PAD / 2);     // NN*16 half2

    int pb = (NCHUNK * NBK + 255) / 256;

    k_phist <<<SCB, 256, 0, stream>>>(dst, partial);
    k_tohalf<<<(NN * (PAD / 2) + 255) / 256, 256, 0, stream>>>(x, xh);
    k_csum  <<<pb, 256, 0, stream>>>(partial, chunksum);
    k_cscan <<<1, 1024, 0, stream>>>(chunksum, chunkbase, bktOff);
    k_base  <<<pb, 256, 0, stream>>>(partial, chunkbase);
    k_bscat <<<SCB, 256, 0, stream>>>(src, dst, partial, pairs);
    k_csr   <<<NBK, 256, 0, stream>>>(bktOff, pairs, rowstart, col);

    k_fused<<<AB, 256, 0, stream>>>(rowstart, col, (const uint4*)xh,
                                    Wl1, bl1, Wr1, FI, g1, b1, m1, v1, h1h);
    k_fused<<<AB, 256, 0, stream>>>(rowstart, col, (const uint4*)h1h,
                                    Wl2, bl2, Wr2, FH, g2, b2, m2, v2, h2h);
    k_pool<<<NG, 256, 0, stream>>>((const __half*)h2h, bat, W1, bb1, W2, bb2, (float*)d_out);
}

// Round 12
// 193.435 us; speedup vs baseline: 1.2691x; 1.2691x over previous
//
#include <hip/hip_runtime.h>
#include <hip/hip_fp16.h>

#define NN 100000
#define NE 1600000
#define FI 32
#define FH 30
#define PAD 32       // row stride (elements) for all feature arrays
#define NG 512
#define NBK 782      // ceil(NN/128) buckets of 128 consecutive dst nodes
#define BNODES 128
#define SCB 1024     // blocks for hist/scatter grid-stride
#define CBLK 32      // blocks per prefix chunk
#define NCHUNK (SCB / CBLK)   // 32
#define CAP 4096     // per-bucket LDS staging capacity (mean 2046)
#define NB1 391      // ceil(NN/256)
#define THB 6250     // tohalf blocks: NN*16 half2 / 256

// ---------- per-block bucket histogram (blocks < SCB) + fp32->fp16 convert (rest) ----------
__global__ __launch_bounds__(256) void k_phist(const int* __restrict__ dst, int* __restrict__ partial,
                                               const float* __restrict__ x, __half2* __restrict__ xh)
{
    __shared__ int cnt[NBK];
    if (blockIdx.x >= SCB) {
        int i = (blockIdx.x - SCB) * 256 + threadIdx.x;   // half2 index
        if (i < NN * (PAD / 2)) {
            float2 f = ((const float2*)x)[i];
            xh[i] = __floats2half2_rn(f.x, f.y);
        }
        return;
    }
    for (int i = threadIdx.x; i < NBK; i += 256) cnt[i] = 0;
    __syncthreads();
    for (int e = blockIdx.x * 256 + threadIdx.x; e < NE; e += SCB * 256)
        atomicAdd(&cnt[dst[e] >> 7], 1);
    __syncthreads();
    for (int i = threadIdx.x; i < NBK; i += 256)
        partial[(size_t)blockIdx.x * NBK + i] = cnt[i];
}

// ---------- chunk sums: chunksum[c][b] = sum of partial over CBLK blocks ----------
__global__ __launch_bounds__(256) void k_csum(const int* __restrict__ partial, int* __restrict__ chunksum)
{
    int t = blockIdx.x * 256 + threadIdx.x;
    if (t >= NCHUNK * NBK) return;
    int c = t / NBK, b = t - c * NBK;
    int s = 0;
    #pragma unroll 8
    for (int k = 0; k < CBLK; ++k)
        s += partial[(size_t)(c * CBLK + k) * NBK + b];
    chunksum[c * NBK + b] = s;
}

// ---------- bucket scan: bktOff (exclusive over buckets) + per-chunk bases ----------
__global__ __launch_bounds__(1024) void k_cscan(const int* __restrict__ chunksum,
                                                int* __restrict__ chunkbase, int* __restrict__ bktOff)
{
    __shared__ int tmp[1024];
    int tid = threadIdx.x;
    int cs[NCHUNK];
    int total = 0;
    if (tid < NBK) {
        #pragma unroll
        for (int c = 0; c < NCHUNK; ++c) { cs[c] = chunksum[c * NBK + tid]; total += cs[c]; }
    }
    tmp[tid] = (tid < NBK) ? total : 0;
    __syncthreads();
    for (int off = 1; off < 1024; off <<= 1) {
        int t = (tid >= off) ? tmp[tid - off] : 0;
        __syncthreads();
        tmp[tid] += t;
        __syncthreads();
    }
    if (tid < NBK) {
        int run = tmp[tid] - total;   // exclusive bucket offset
        bktOff[tid] = run;
        #pragma unroll
        for (int c = 0; c < NCHUNK; ++c) { chunkbase[c * NBK + tid] = run; run += cs[c]; }
    }
    if (tid == 0) bktOff[NBK] = NE;
}

// ---------- per-block bases: partial[blk][b] <- global write base (in-place prefix) ----------
__global__ __launch_bounds__(256) void k_base(int* __restrict__ partial, const int* __restrict__ chunkbase)
{
    int t = blockIdx.x * 256 + threadIdx.x;
    if (t >= NCHUNK * NBK) return;
    int c = t / NBK, b = t - c * NBK;
    int run = chunkbase[c * NBK + b];
    #pragma unroll 8
    for (int k = 0; k < CBLK; ++k) {
        size_t idx = (size_t)(c * CBLK + k) * NBK + b;
        int v = partial[idx];
        partial[idx] = run;
        run += v;
    }
}

// ---------- single-pass bucketed scatter using precomputed bases ----------
__global__ __launch_bounds__(256) void k_bscat(const int* __restrict__ src, const int* __restrict__ dst,
                                               const int* __restrict__ partial, unsigned* __restrict__ pairs)
{
    __shared__ int sbase[NBK];
    __shared__ int scnt[NBK];
    for (int i = threadIdx.x; i < NBK; i += 256) {
        sbase[i] = partial[(size_t)blockIdx.x * NBK + i];
        scnt[i] = 0;
    }
    __syncthreads();
    for (int e = blockIdx.x * 256 + threadIdx.x; e < NE; e += SCB * 256) {
        int d = dst[e];
        int b = d >> 7;
        int r = atomicAdd(&scnt[b], 1);
        pairs[sbase[b] + r] = ((unsigned)src[e] << 7) | (unsigned)(d & 127);
    }
}

// ---------- per-bucket counting sort -> CSR ----------
__global__ __launch_bounds__(256) void k_csr(
    const int* __restrict__ bktOff, const unsigned* __restrict__ pairs,
    int* __restrict__ rowstart, int* __restrict__ col)
{
    __shared__ unsigned sp[CAP];
    __shared__ int bins[BNODES], binpos[BNODES], stmp[BNODES];
    int tid = threadIdx.x;
    int bkt = blockIdx.x;
    int gbase = bktOff[bkt];
    int cnt = bktOff[bkt + 1] - gbase;
    if (tid < BNODES) bins[tid] = 0;
    __syncthreads();
    bool inl = (cnt <= CAP);
    if (inl) {
        for (int i = tid; i < cnt; i += 256) {
            unsigned u = pairs[gbase + i];
            sp[i] = u;
            atomicAdd(&bins[u & 127], 1);
        }
    } else {
        for (int i = tid; i < cnt; i += 256)
            atomicAdd(&bins[pairs[gbase + i] & 127], 1);
    }
    __syncthreads();
    if (tid < BNODES) stmp[tid] = bins[tid];
    __syncthreads();
    for (int off = 1; off < BNODES; off <<= 1) {
        int t = 0;
        if (tid < BNODES && tid >= off) t = stmp[tid - off];
        __syncthreads();
        if (tid < BNODES) stmp[tid] += t;
        __syncthreads();
    }
    if (tid < BNODES) {
        int ex = stmp[tid] - bins[tid];
        binpos[tid] = ex;
        int n = (bkt << 7) + tid;
        if (n < NN) rowstart[n] = gbase + ex;
        if (bkt == 0 && tid == 0) rowstart[NN] = NE;
    }
    __syncthreads();
    if (inl) {
        for (int i = tid; i < cnt; i += 256) {
            unsigned u = sp[i];
            int p = atomicAdd(&binpos[u & 127], 1);
            col[gbase + p] = (int)(u >> 7);
        }
    } else {
        for (int i = tid; i < cnt; i += 256) {
            unsigned u = pairs[gbase + i];
            int p = atomicAdd(&binpos[u & 127], 1);
            col[gbase + p] = (int)(u >> 7);
        }
    }
}

// ---------- CSR mean aggregation from fp16 rows ----------
// one wave per node; 4 lanes/edge x 16B loads -> 16 row-gathers in flight per iter
__global__ __launch_bounds__(256) void k_aggcsr_h(const int* __restrict__ rowstart,
                                                  const int* __restrict__ col,
                                                  const uint4* __restrict__ hin,  // 4 uint4 per row
                                                  float* __restrict__ aggout)
{
    int tid = blockIdx.x * 256 + threadIdx.x;
    int n = tid >> 6;
    if (n >= NN) return;
    int lane = threadIdx.x & 63;
    int q = lane & 3;       // uint4 (8-half) block within the 32-half row
    int grp = lane >> 2;    // edge group 0..15
    int rs = rowstart[n], re = rowstart[n + 1];
    float a0 = 0.0f, a1 = 0.0f, a2 = 0.0f, a3 = 0.0f;
    float a4 = 0.0f, a5 = 0.0f, a6 = 0.0f, a7 = 0.0f;
    for (int e = rs + grp; e < re; e += 16) {
        uint4 u = hin[(size_t)col[e] * 4 + q];
        float2 f0 = __half22float2(*(const __half2*)&u.x);
        float2 f1 = __half22float2(*(const __half2*)&u.y);
        float2 f2 = __half22float2(*(const __half2*)&u.z);
        float2 f3 = __half22float2(*(const __half2*)&u.w);
        a0 += f0.x; a1 += f0.y; a2 += f1.x; a3 += f1.y;
        a4 += f2.x; a5 += f2.y; a6 += f3.x; a7 += f3.y;
    }
    #pragma unroll
    for (int off = 4; off < 64; off <<= 1) {
        a0 += __shfl_xor(a0, off); a1 += __shfl_xor(a1, off);
        a2 += __shfl_xor(a2, off); a3 += __shfl_xor(a3, off);
        a4 += __shfl_xor(a4, off); a5 += __shfl_xor(a5, off);
        a6 += __shfl_xor(a6, off); a7 += __shfl_xor(a7, off);
    }
    if (lane < 4) {
        float inv = (re > rs) ? 1.0f / (float)(re - rs) : 0.0f;
        float4* o = (float4*)(aggout + (size_t)n * PAD + q * 8);
        o[0] = make_float4(a0 * inv, a1 * inv, a2 * inv, a3 * inv);
        o[1] = make_float4(a4 * inv, a5 * inv, a6 * inv, a7 * inv);
    }
}

// ---------- layer-1 transform: h1h(fp16) = bn(relu(agg@Wl^T + bl + x@Wr^T)) ----------
__global__ __launch_bounds__(256) void k_t1(
    const float* __restrict__ x, const float* __restrict__ agg,
    const float* __restrict__ Wl, const float* __restrict__ bl, const float* __restrict__ Wr,
    const float* __restrict__ g, const float* __restrict__ b,
    const float* __restrict__ m, const float* __restrict__ v,
    __half2* __restrict__ h1h)
{
    __shared__ float sWl[FH * FI], sWr[FH * FI], sBias[FH], sScale[FH], sShift[FH];
    for (int i = threadIdx.x; i < FH * FI; i += 256) { sWl[i] = Wl[i]; sWr[i] = Wr[i]; }
    if (threadIdx.x < FH) {
        int j = threadIdx.x;
        float sc = g[j] * rsqrtf(v[j] + 1e-5f);
        sBias[j] = bl[j];
        sScale[j] = sc;
        sShift[j] = b[j] - m[j] * sc;
    }
    __syncthreads();
    int n = blockIdx.x * 256 + threadIdx.x;
    if (n >= NN) return;
    float xr[FI], ar[FI];
    #pragma unroll
    for (int k = 0; k < FI; k += 4) {
        float4 xv = *(const float4*)(x + (size_t)n * FI + k);
        float4 av = *(const float4*)(agg + (size_t)n * PAD + k);
        xr[k] = xv.x; xr[k+1] = xv.y; xr[k+2] = xv.z; xr[k+3] = xv.w;
        ar[k] = av.x; ar[k+1] = av.y; ar[k+2] = av.z; ar[k+3] = av.w;
    }
    float res[FH];
    for (int j = 0; j < FH; ++j) {
        float acc = sBias[j];
        #pragma unroll
        for (int k = 0; k < FI; ++k)
            acc += ar[k] * sWl[j * FI + k] + xr[k] * sWr[j * FI + k];
        acc = fmaxf(acc, 0.0f);
        res[j] = acc * sScale[j] + sShift[j];
    }
    __half2* row = h1h + (size_t)n * (PAD / 2);
    #pragma unroll
    for (int j = 0; j < FH; j += 2)
        row[j >> 1] = __floats2half2_rn(res[j], res[j + 1]);
    row[15] = __floats2half2_rn(0.0f, 0.0f);   // zero pad: wide gathers read it
}

// ---------- layer-2 transform: h2h(fp16) = bn(relu(agg@Wl^T + bl + h1@Wr^T)) ----------
__global__ __launch_bounds__(256) void k_t2(
    const __half2* __restrict__ h1h, const float* __restrict__ agg,
    const float* __restrict__ Wl, const float* __restrict__ bl, const float* __restrict__ Wr,
    const float* __restrict__ g, const float* __restrict__ b,
    const float* __restrict__ m, const float* __restrict__ v,
    __half2* __restrict__ h2h)
{
    __shared__ float sWl[FH * FH], sWr[FH * FH], sBias[FH], sScale[FH], sShift[FH];
    for (int i = threadIdx.x; i < FH * FH; i += 256) { sWl[i] = Wl[i]; sWr[i] = Wr[i]; }
    if (threadIdx.x < FH) {
        int j = threadIdx.x;
        float sc = g[j] * rsqrtf(v[j] + 1e-5f);
        sBias[j] = bl[j];
        sScale[j] = sc;
        sShift[j] = b[j] - m[j] * sc;
    }
    __syncthreads();
    int n = blockIdx.x * 256 + threadIdx.x;
    if (n >= NN) return;
    float xr[FH], ar[FH];
    const __half2* hrow = h1h + (size_t)n * (PAD / 2);
    #pragma unroll
    for (int k2 = 0; k2 < FH / 2; ++k2) {
        float2 fv = __half22float2(hrow[k2]);
        xr[2 * k2] = fv.x; xr[2 * k2 + 1] = fv.y;
    }
    #pragma unroll
    for (int k = 0; k < FH; ++k)
        ar[k] = agg[(size_t)n * PAD + k];
    float res[FH];
    for (int j = 0; j < FH; ++j) {
        float acc = sBias[j];
        #pragma unroll
        for (int k = 0; k < FH; ++k)
            acc += ar[k] * sWl[j * FH + k] + xr[k] * sWr[j * FH + k];
        acc = fmaxf(acc, 0.0f);
        res[j] = acc * sScale[j] + sShift[j];
    }
    __half2* row = h2h + (size_t)n * (PAD / 2);
    #pragma unroll
    for (int j = 0; j < FH; j += 2)
        row[j >> 1] = __floats2half2_rn(res[j], res[j + 1]);
    row[15] = __floats2half2_rn(0.0f, 0.0f);
}

// ---------- per-graph dual pooling + MLP (fp16 input) ----------
__global__ __launch_bounds__(256) void k_pool(
    const __half* __restrict__ h2, const int* __restrict__ batch,
    const float* __restrict__ W1, const float* __restrict__ bb1,
    const float* __restrict__ W2, const float* __restrict__ bb2,
    float* __restrict__ out)
{
    __shared__ float sS[8][FH], sM[8][FH], sz[2 * FH], st[10];
    int tid = threadIdx.x;
    int gi = blockIdx.x;
    int lo = 0, hi = NN;
    while (lo < hi) { int mid = (lo + hi) >> 1; if (batch[mid] < gi) lo = mid + 1; else hi = mid; }
    int start = lo;
    hi = NN;
    while (lo < hi) { int mid = (lo + hi) >> 1; if (batch[mid] <= gi) lo = mid + 1; else hi = mid; }
    int end = lo;

    int f = tid & 31;
    int ng = tid >> 5;
    float sum = 0.0f, mx = -INFINITY;
    if (f < FH) {
        for (int n = start + ng; n < end; n += 8) {
            float val = __half2float(h2[(size_t)n * PAD + f]);
            sum += val;
            mx = fmaxf(mx, val);
        }
        sS[ng][f] = sum;
        sM[ng][f] = mx;
    }
    __syncthreads();
    if (tid < FH) {
        float s = 0.0f, mm = -INFINITY;
        #pragma unroll
        for (int w = 0; w < 8; ++w) { s += sS[w][tid]; mm = fmaxf(mm, sM[w][tid]); }
        int c = end - start;
        sz[tid]      = (c > 0) ? mm : 0.0f;
        sz[FH + tid] = (c > 0) ? s / (float)c : 0.0f;
    }
    __syncthreads();
    if (tid < 10) {
        float t = bb1[tid];
        for (int k = 0; k < 2 * FH; ++k) t += sz[k] * W1[tid * 2 * FH + k];
        st[tid] = fmaxf(t, 0.0f);
    }
    __syncthreads();
    if (tid == 0) {
        float o = bb2[0];
        for (int j = 0; j < 10; ++j) o += st[j] * W2[j];
        out[gi] = 1.0f / (1.0f + expf(-o));
    }
}

extern "C" void kernel_launch(void* const* d_in, const int* in_sizes, int n_in,
                              void* d_out, int out_size, void* d_ws, size_t ws_size,
                              hipStream_t stream)
{
    const float* x   = (const float*)d_in[0];
    const int*   ei  = (const int*)d_in[1];
    const int*   bat = (const int*)d_in[2];
    const float* Wl1 = (const float*)d_in[3];
    const float* bl1 = (const float*)d_in[4];
    const float* Wr1 = (const float*)d_in[5];
    const float* Wl2 = (const float*)d_in[6];
    const float* bl2 = (const float*)d_in[7];
    const float* Wr2 = (const float*)d_in[8];
    const float* g1  = (const float*)d_in[9];
    const float* b1  = (const float*)d_in[10];
    const float* m1  = (const float*)d_in[11];
    const float* v1  = (const float*)d_in[12];
    const float* g2  = (const float*)d_in[13];
    const float* b2  = (const float*)d_in[14];
    const float* m2  = (const float*)d_in[15];
    const float* v2  = (const float*)d_in[16];
    const float* W1  = (const float*)d_in[17];
    const float* bb1 = (const float*)d_in[18];
    const float* W2  = (const float*)d_in[19];
    const float* bb2 = (const float*)d_in[20];

    const int* src = ei;
    const int* dst = ei + NE;

    // workspace layout (4B words; every region starts at a multiple of 4 words = 16B)
    int* wsi = (int*)d_ws;
    int*      partial   = wsi;                              // SCB*NBK = 800768
    int*      chunksum  = partial + (size_t)SCB * NBK;      // NCHUNK*NBK = 25024
    int*      chunkbase = chunksum + NCHUNK * NBK;          // 25024
    int*      bktOff    = chunkbase + NCHUNK * NBK;         // 784 (incl pad)
    int*      rowstart  = bktOff + NBK + 2;                 // 100004 (incl pad)
    unsigned* pairs     = (unsigned*)(rowstart + NN + 4);   // NE
    int*      col       = (int*)(pairs + NE);               // NE
    __half2*  xh        = (__half2*)(col + NE);             // NN*16 half2
    __half2*  h1h       = xh + (size_t)NN * (PAD / 2);      // NN*16 half2
    __half2*  h2h       = h1h + (size_t)NN * (PAD / 2);     // NN*16 half2
    float*    aggbuf    = (float*)(h2h + (size_t)NN * (PAD / 2)); // NN*PAD fp32

    int pb = (NCHUNK * NBK + 255) / 256;  // 98 blocks

    k_phist <<<SCB + THB, 256, 0, stream>>>(dst, partial, x, xh);
    k_csum  <<<pb, 256, 0, stream>>>(partial, chunksum);
    k_cscan <<<1, 1024, 0, stream>>>(chunksum, chunkbase, bktOff);
    k_base  <<<pb, 256, 0, stream>>>(partial, chunkbase);
    k_bscat <<<SCB, 256, 0, stream>>>(src, dst, partial, pairs);
    k_csr   <<<NBK, 256, 0, stream>>>(bktOff, pairs, rowstart, col);

    int ab = (NN * 64 + 255) / 256;  // one wave per node
    k_aggcsr_h<<<ab, 256, 0, stream>>>(rowstart, col, (const uint4*)xh, aggbuf);
    k_t1<<<NB1, 256, 0, stream>>>(x, aggbuf, Wl1, bl1, Wr1, g1, b1, m1, v1, h1h);
    k_aggcsr_h<<<ab, 256, 0, stream>>>(rowstart, col, (const uint4*)h1h, aggbuf);
    k_t2<<<NB1, 256, 0, stream>>>(h1h, aggbuf, Wl2, bl2, Wr2, g2, b2, m2, v2, h2h);
    k_pool<<<NG, 256, 0, stream>>>((const __half*)h2h, bat, W1, bb1, W2, bb2, (float*)d_out);
}